// Round 1
// baseline (564.654 us; speedup 1.0000x reference)
//
#include <hip/hip_runtime.h>

// One thread per Gaussian. Memory-bound element-wise op.
// Inputs (setup_inputs order): 0=xyz(unused), 1=scaling_raw (N,3),
// 2=rotation (N,4), 3=opacity_raw (N,1), 4=features (N,16,3),
// 5=viewmatrix(unused), 6=projmatrix(unused).
// Output: cov3d(9N) | cov2d(4N) | color(3N) | opacity(N), all f32.

__global__ __launch_bounds__(256) void gauss_props_kernel(
    const float*  __restrict__ scaling_raw,   // (N,3)
    const float4* __restrict__ rotation,      // (N,4) as float4
    const float*  __restrict__ opacity_raw,   // (N,1)
    const float*  __restrict__ features,      // (N,16,3)
    float* __restrict__ out, int N)
{
    int n = blockIdx.x * blockDim.x + threadIdx.x;
    if (n >= N) return;

    // --- quaternion -> rotation matrix ---
    float4 q = rotation[n];
    float inv = rsqrtf(q.x * q.x + q.y * q.y + q.z * q.z + q.w * q.w);
    float w = q.x * inv, x = q.y * inv, y = q.z * inv, z = q.w * inv;

    float xx = x * x, yy = y * y, zz = z * z;
    float wx = w * x, wy = w * y, wz = w * z;
    float xy = x * y, xz = x * z, yz = y * z;

    float R[3][3];
    R[0][0] = 1.f - 2.f * (yy + zz); R[0][1] = 2.f * (xy - wz); R[0][2] = 2.f * (xz + wy);
    R[1][0] = 2.f * (xy + wz); R[1][1] = 1.f - 2.f * (xx + zz); R[1][2] = 2.f * (yz - wx);
    R[2][0] = 2.f * (xz - wy); R[2][1] = 2.f * (yz + wx); R[2][2] = 1.f - 2.f * (xx + yy);

    // --- sigma^2 = exp(scaling)^2 = exp(2*scaling) ---
    float s0 = __expf(2.f * scaling_raw[3 * n + 0]);
    float s1 = __expf(2.f * scaling_raw[3 * n + 1]);
    float s2 = __expf(2.f * scaling_raw[3 * n + 2]);

    // --- cov3d[i][k] = sum_j R[i][j] * s_j * R[k][j] (symmetric) ---
    float cov[3][3];
    #pragma unroll
    for (int i = 0; i < 3; ++i)
        #pragma unroll
        for (int k = 0; k < 3; ++k)
            cov[i][k] = R[i][0] * R[k][0] * s0 + R[i][1] * R[k][1] * s1 + R[i][2] * R[k][2] * s2;

    float var = (cov[0][0] + cov[1][1] + cov[2][2]) * (1.f / 3.f);

    // --- opacity = sigmoid(opacity_raw) ---
    float o = opacity_raw[n];
    float opac = 1.f / (1.f + __expf(-o));

    // --- color = features[n, 0, :] ---
    float c0 = features[(size_t)48 * n + 0];
    float c1 = features[(size_t)48 * n + 1];
    float c2 = features[(size_t)48 * n + 2];

    // --- writes ---
    size_t Ns = (size_t)N;
    float* out_cov3d = out;                       // 9N
    float* out_cov2d = out + 9 * Ns;              // 4N
    float* out_color = out + 13 * Ns;             // 3N
    float* out_opac  = out + 16 * Ns;             // N

    size_t b9 = (size_t)9 * n;
    #pragma unroll
    for (int i = 0; i < 3; ++i)
        #pragma unroll
        for (int k = 0; k < 3; ++k)
            out_cov3d[b9 + 3 * i + k] = cov[i][k];

    size_t b4 = (size_t)4 * n;
    out_cov2d[b4 + 0] = var;
    out_cov2d[b4 + 1] = 0.f;
    out_cov2d[b4 + 2] = 0.f;
    out_cov2d[b4 + 3] = var;

    size_t b3 = (size_t)3 * n;
    out_color[b3 + 0] = c0;
    out_color[b3 + 1] = c1;
    out_color[b3 + 2] = c2;

    out_opac[n] = opac;
}

extern "C" void kernel_launch(void* const* d_in, const int* in_sizes, int n_in,
                              void* d_out, int out_size, void* d_ws, size_t ws_size,
                              hipStream_t stream) {
    const float*  scaling  = (const float*)d_in[1];
    const float4* rotation = (const float4*)d_in[2];
    const float*  opacity  = (const float*)d_in[3];
    const float*  features = (const float*)d_in[4];
    float* out = (float*)d_out;

    int N = in_sizes[3]; // opacity_raw has N elements
    int threads = 256;
    int blocks = (N + threads - 1) / threads;
    gauss_props_kernel<<<blocks, threads, 0, stream>>>(scaling, rotation, opacity,
                                                       features, out, N);
}